// Round 6
// baseline (1500.105 us; speedup 1.0000x reference)
//
#include <hip/hip_runtime.h>
#include <hip/hip_bf16.h>

using bf16s = __hip_bfloat16;
typedef __bf16 bf16x8 __attribute__((ext_vector_type(8)));
typedef float f32x4 __attribute__((ext_vector_type(4)));
typedef unsigned short u16x8 __attribute__((ext_vector_type(8)));

constexpr int MS_TILE = 2048;
constexpr int BSH = 7;                 // 128-node buckets
constexpr int BNODES = 128;
constexpr int NBUCK_MAX = 1024;
constexpr int SLAB_CAP = 2560;         // mean fill 2048, sigma 45 -> 11 sigma slack

__device__ inline float uasf(unsigned u) { return __uint_as_float(u); }

// pack two f32 -> bf16x2 dword (RNE), x in low half, y in high half
__device__ inline unsigned pk2(float x, float y) {
    unsigned ux = __float_as_uint(x), uy = __float_as_uint(y);
    ux = (ux + 0x7fffu + ((ux >> 16) & 1u)) >> 16;
    uy = (uy + 0x7fffu + ((uy >> 16) & 1u)) & 0xffff0000u;
    return (ux & 0xffffu) | uy;
}

// ---------------- multisplit: partition edges into 128-node coarse bucket slabs ----
// Appends packed (src<<7 | dst&127) ints into slab b*SLAB_CAP, coalesced runs.
__global__ __launch_bounds__(256) void multisplit(const int* __restrict__ src,
                                                  const int* __restrict__ dst,
                                                  int* __restrict__ gcur,
                                                  int* __restrict__ part, int E) {
    __shared__ int cnt[NBUCK_MAX];
    __shared__ int off[NBUCK_MAX];
    __shared__ int gbase[NBUCK_MAX];
    __shared__ int img[MS_TILE];
    __shared__ int tgt[MS_TILE];
    int tid = threadIdx.x;
    for (int tbase = blockIdx.x * MS_TILE; tbase < E; tbase += gridDim.x * MS_TILE) {
        int m = min(MS_TILE, E - tbase);
        for (int i = tid; i < NBUCK_MAX; i += 256) cnt[i] = 0;
        __syncthreads();
        int pk[8], bk[8], rk[8];
        int nloc = 0;
        int j0 = tid * 8;
        if (j0 + 8 <= m) {
            int4 s0 = *(const int4*)(src + tbase + j0);
            int4 s1 = *(const int4*)(src + tbase + j0 + 4);
            int4 d0 = *(const int4*)(dst + tbase + j0);
            int4 d1 = *(const int4*)(dst + tbase + j0 + 4);
            int ss[8] = {s0.x, s0.y, s0.z, s0.w, s1.x, s1.y, s1.z, s1.w};
            int dd[8] = {d0.x, d0.y, d0.z, d0.w, d1.x, d1.y, d1.z, d1.w};
#pragma unroll
            for (int k = 0; k < 8; k++) {
                int b = dd[k] >> BSH;
                pk[k] = (ss[k] << BSH) | (dd[k] & (BNODES - 1));
                bk[k] = b;
                rk[k] = atomicAdd(&cnt[b], 1);
            }
            nloc = 8;
        } else {
            for (int j = j0; j < m; j++) {
                int s = src[tbase + j], d = dst[tbase + j];
                int b = d >> BSH;
                pk[nloc] = (s << BSH) | (d & (BNODES - 1));
                bk[nloc] = b;
                rk[nloc] = atomicAdd(&cnt[b], 1);
                nloc++;
            }
        }
        __syncthreads();
        // exclusive scan of cnt[0..1024) by wave 0 (64 lanes x 16 serial)
        if (tid < 64) {
            int base = tid * 16;
            int vals[16];
            int s0 = 0;
#pragma unroll
            for (int j = 0; j < 16; j++) { vals[j] = cnt[base + j]; s0 += vals[j]; }
            int sc = s0;
#pragma unroll
            for (int o = 1; o < 64; o <<= 1) {
                int u = __shfl_up(sc, o);
                if (tid >= o) sc += u;
            }
            int ex = sc - s0;
#pragma unroll
            for (int j = 0; j < 16; j++) { off[base + j] = ex; ex += vals[j]; }
        }
        __syncthreads();
        // reserve slab space per bucket (one atomic per WG per nonempty bucket)
        for (int b = tid; b < NBUCK_MAX; b += 256) {
            int c = cnt[b];
            if (c) {
                int st = atomicAdd(&gcur[b], c);
                if (st > SLAB_CAP - c) st = SLAB_CAP - c;   // defensive; never in practice
                gbase[b] = b * SLAB_CAP + st;
            }
        }
        __syncthreads();
        // scatter into LDS, grouped by bucket
        for (int i = 0; i < nloc; i++) {
            int p = off[bk[i]] + rk[i];
            img[p] = pk[i];
            tgt[p] = gbase[bk[i]] + rk[i];
        }
        __syncthreads();
        // coalesced write-out (consecutive slots -> consecutive targets per bucket run)
        for (int j = tid; j < m; j += 256) part[tgt[j]] = img[j];
        __syncthreads();
    }
}

// ---------------- deg_dinv: per-bucket degree histogram -> dinv ----------------
__global__ __launch_bounds__(256) void deg_dinv(const int* __restrict__ gcur,
                                                const int* __restrict__ part,
                                                float* __restrict__ dinv, int n) {
    __shared__ int deg[BNODES];
    int b = blockIdx.x;
    int tid = threadIdx.x;
    int m = min(gcur[b], SLAB_CAP);
    const int* slab = part + b * SLAB_CAP;
    if (tid < BNODES) deg[tid] = 0;
    __syncthreads();
    for (int j = tid; j < m; j += 256) atomicAdd(&deg[slab[j] & (BNODES - 1)], 1);
    __syncthreads();
    int node = (b << BSH) + tid;
    if (tid < BNODES && node < n) dinv[node] = rsqrtf((float)(deg[tid] + 1));
}

// ---- GEMM + dinv prescale: t[r] = bf16x2-permuted(dinv[r] * (A[r] @ W)) ----
// Output layout: dword c of row = feats (c | (c+32)<<16). MFMA 16x16x32.
template <bool AF32>
__global__ __launch_bounds__(256) void gemm64(const void* __restrict__ A_,
                                              const float* __restrict__ W,
                                              const float* __restrict__ dinv,
                                              unsigned* __restrict__ out32, int nrows) {
    int lane = threadIdx.x & 63;
    int wid = (blockIdx.x * blockDim.x + threadIdx.x) >> 6;
    int nwaves = (gridDim.x * blockDim.x) >> 6;
    int r = lane & 15;       // col-in-tile
    int q = lane >> 4;       // quad
    int kb = q * 8;

    // B fragments: 4 n-tiles x 2 k-halves. B[k][n]: n=lane&15, k=quad*8+j
    bf16x8 bfrag[4][2];
#pragma unroll
    for (int t = 0; t < 4; t++) {
#pragma unroll
        for (int h = 0; h < 2; h++) {
            bf16x8 bb;
            int ncol = t * 16 + r;
            int k0 = h * 32 + kb;
#pragma unroll
            for (int j = 0; j < 8; j++) bb[j] = (__bf16)W[(k0 + j) * 64 + ncol];
            bfrag[t][h] = bb;
        }
    }

    int ntiles = nrows >> 4;
    for (int tile = wid; tile < ntiles; tile += nwaves) {
        bf16x8 a0, a1;
        if (AF32) {
            // standard fp32 layout: feats kb..kb+7 -> a0, 32+kb.. -> a1
            const float* ap = (const float*)A_ + (size_t)(tile * 16 + r) * 64 + kb;
            f32x4 v0 = *reinterpret_cast<const f32x4*>(ap);
            f32x4 v1 = *reinterpret_cast<const f32x4*>(ap + 4);
            f32x4 v2 = *reinterpret_cast<const f32x4*>(ap + 32);
            f32x4 v3 = *reinterpret_cast<const f32x4*>(ap + 36);
#pragma unroll
            for (int j = 0; j < 4; j++) {
                a0[j] = (__bf16)v0[j]; a0[4 + j] = (__bf16)v1[j];
                a1[j] = (__bf16)v2[j]; a1[4 + j] = (__bf16)v3[j];
            }
        } else {
            // permuted bf16 layout: dwords kb..kb+7 -> lows = a0 feats, highs = a1 feats
            const unsigned* ap = (const unsigned*)A_ + (size_t)(tile * 16 + r) * 32 + kb;
            uint4 w0 = *(const uint4*)ap;
            uint4 w1 = *(const uint4*)(ap + 4);
            unsigned wv[8] = {w0.x, w0.y, w0.z, w0.w, w1.x, w1.y, w1.z, w1.w};
            u16x8 lo, hi;
#pragma unroll
            for (int j = 0; j < 8; j++) {
                lo[j] = (unsigned short)(wv[j] & 0xffffu);
                hi[j] = (unsigned short)(wv[j] >> 16);
            }
            a0 = __builtin_bit_cast(bf16x8, lo);
            a1 = __builtin_bit_cast(bf16x8, hi);
        }
        f32x4 c[4];
#pragma unroll
        for (int t = 0; t < 4; t++) {
            f32x4 acc = {0.f, 0.f, 0.f, 0.f};
            acc = __builtin_amdgcn_mfma_f32_16x16x32_bf16(a0, bfrag[t][0], acc, 0, 0, 0);
            acc = __builtin_amdgcn_mfma_f32_16x16x32_bf16(a1, bfrag[t][1], acc, 0, 0, 0);
            c[t] = acc;
        }
        // C/D layout: col(feat) = t*16 + r, row = tile*16 + quad*4 + reg
        // dword r   = feats (r,   r+32 ) = tiles 0,2 ; dword 16+r = feats (16+r, 48+r) = tiles 1,3
        float dr[4];
#pragma unroll
        for (int g = 0; g < 4; g++) dr[g] = dinv[tile * 16 + q * 4 + g];
#pragma unroll
        for (int g = 0; g < 4; g++) {
            size_t row = (size_t)(tile * 16 + q * 4 + g);
            out32[row * 32 + r]      = pk2(c[0][g] * dr[g], c[2][g] * dr[g]);
            out32[row * 32 + 16 + r] = pk2(c[1][g] * dr[g], c[3][g] * dr[g]);
        }
    }
}

// ---------------- aggregate (push): one WG per 128-node bucket ----------------
// LDS fp32 accumulator [node][feat]; edges streamed from slab; t pre-scaled by
// dinv[src] and bf16x2-permuted. out = relu(dinv[v]*(sum_e t[s] + t[v]) + bias)
template <bool OUTF32>
__global__ __launch_bounds__(256) void aggregate(const unsigned* __restrict__ t32,
                                                 const float* __restrict__ dinv,
                                                 const int* __restrict__ gcur,
                                                 const int* __restrict__ part,
                                                 const float* __restrict__ bias,
                                                 void* __restrict__ out_, int n) {
    __shared__ float acc[BNODES * 64];   // 32 KB
    int b = blockIdx.x;
    int tid = threadIdx.x;
    int node0 = b << BSH;
    int m = min(gcur[b], SLAB_CAP);
    const int* slab = part + b * SLAB_CAP;

    f32x4* a4 = (f32x4*)acc;
    f32x4 z = {0.f, 0.f, 0.f, 0.f};
    for (int i = tid; i < BNODES * 16; i += 256) a4[i] = z;
    __syncthreads();

    int wv = tid >> 6;        // wave 0..3
    int lane = tid & 63;
    int half = lane >> 5;
    int c = lane & 31;
    // wave edge range, halves take contiguous sub-ranges (int4-loadable)
    int w0 = (int)(((long)m * wv) >> 2);
    int w1 = (int)(((long)m * (wv + 1)) >> 2);
    int hcnt = (w1 - w0 + 1) >> 1;
    int hb = half ? (w0 + hcnt) : w0;
    int he = half ? w1 : (w0 + hcnt);

    int j = hb;
    for (; j + 16 <= he; j += 16) {     // 16 edges per half per iter, 16 gathers in flight
        int4 p0 = *(const int4*)(slab + j);
        int4 p1 = *(const int4*)(slab + j + 4);
        int4 p2 = *(const int4*)(slab + j + 8);
        int4 p3 = *(const int4*)(slab + j + 12);
        int pe[16] = {p0.x, p0.y, p0.z, p0.w, p1.x, p1.y, p1.z, p1.w,
                      p2.x, p2.y, p2.z, p2.w, p3.x, p3.y, p3.z, p3.w};
        unsigned g[16];
#pragma unroll
        for (int k = 0; k < 16; k++)
            g[k] = t32[(size_t)(((unsigned)pe[k]) >> BSH) * 32 + c];
#pragma unroll
        for (int k = 0; k < 16; k++) {
            int dl = pe[k] & (BNODES - 1);
            atomicAdd(&acc[dl * 64 + c], uasf(g[k] << 16));
            atomicAdd(&acc[dl * 64 + 32 + c], uasf(g[k] & 0xffff0000u));
        }
    }
    for (; j < he; j++) {
        int pe = slab[j];
        unsigned g = t32[(size_t)(((unsigned)pe) >> BSH) * 32 + c];
        int dl = pe & (BNODES - 1);
        atomicAdd(&acc[dl * 64 + c], uasf(g << 16));
        atomicAdd(&acc[dl * 64 + 32 + c], uasf(g & 0xffff0000u));
    }
    __syncthreads();

    // self term + epilogue: 128 nodes x 32 dwords, coalesced
    for (int idx = tid; idx < BNODES * 32; idx += 256) {
        int node = idx >> 5, cc = idx & 31;
        int gn = node0 + node;
        if (gn < n) {
            unsigned w = t32[(size_t)gn * 32 + cc];
            float lo = uasf(w << 16) + acc[node * 64 + cc];
            float hi = uasf(w & 0xffff0000u) + acc[node * 64 + 32 + cc];
            float dv = dinv[gn];
            float ox = fmaxf(fmaf(dv, lo, bias[cc]), 0.f);
            float oy = fmaxf(fmaf(dv, hi, bias[cc + 32]), 0.f);
            if (OUTF32) {
                float* o = (float*)out_;
                o[(size_t)gn * 64 + cc] = ox;
                o[(size_t)gn * 64 + 32 + cc] = oy;
            } else {
                ((unsigned*)out_)[(size_t)gn * 32 + cc] = pk2(ox, oy);
            }
        }
    }
}

extern "C" void kernel_launch(void* const* d_in, const int* in_sizes, int n_in,
                              void* d_out, int out_size, void* d_ws, size_t ws_size,
                              hipStream_t stream) {
    const float* x  = (const float*)d_in[0];
    const int*   ei = (const int*)d_in[1];
    const float* W1 = (const float*)d_in[2];
    const float* b1 = (const float*)d_in[3];
    const float* W2 = (const float*)d_in[4];
    const float* b2 = (const float*)d_in[5];
    float* out = (float*)d_out;

    int n = in_sizes[0] / 64;   // 100000
    int E = in_sizes[1] / 2;    // 1600000
    const int* src = ei;
    const int* dst = ei + E;
    int nbuck = (n + BNODES - 1) >> BSH;   // 782

    // workspace carve
    char* w = (char*)d_ws;
    auto alloc = [&](size_t bytes) -> void* {
        void* p = (void*)w;
        w += (bytes + 255) & ~(size_t)255;
        return p;
    };
    int*      gcur = (int*)alloc(NBUCK_MAX * 4);
    float*    dinv = (float*)alloc((size_t)n * 4);
    int*      part = (int*)alloc((size_t)nbuck * SLAB_CAP * 4);   // ~8 MB, live whole call
    unsigned* tbuf = (unsigned*)alloc((size_t)n * 32 * 4);        // 12.8 MB (bf16x2 permuted)
    unsigned* h1   = (unsigned*)alloc((size_t)n * 32 * 4);        // 12.8 MB

    hipMemsetAsync(gcur, 0, NBUCK_MAX * 4, stream);

    int ntiles = (E + MS_TILE - 1) / MS_TILE;   // 782
    multisplit<<<ntiles, 256, 0, stream>>>(src, dst, gcur, part, E);
    deg_dinv<<<nbuck, 256, 0, stream>>>(gcur, part, dinv, n);

    // layer 1
    gemm64<true><<<256, 256, 0, stream>>>(x, W1, dinv, tbuf, n);
    aggregate<false><<<nbuck, 256, 0, stream>>>(tbuf, dinv, gcur, part, b1, h1, n);
    // layer 2
    gemm64<false><<<256, 256, 0, stream>>>(h1, W2, dinv, tbuf, n);
    aggregate<true><<<nbuck, 256, 0, stream>>>(tbuf, dinv, gcur, part, b2, out, n);
}

// Round 7
// 205.448 us; speedup vs baseline: 7.3016x; 7.3016x over previous
//
#include <hip/hip_runtime.h>
#include <hip/hip_bf16.h>

using bf16s = __hip_bfloat16;
typedef __bf16 bf16x8 __attribute__((ext_vector_type(8)));
typedef float f32x4 __attribute__((ext_vector_type(4)));

constexpr int MS_TILE = 2048;
constexpr int SLAB_CAP = 5120;   // 256-node buckets: mean fill 4096, sigma 64 -> 16 sigma
constexpr int CSR_CAP = 7168;    // SLAB_CAP + 256*7 pad worst case, rounded up

__device__ inline float uasf(unsigned u) { return __uint_as_float(u); }

// pack two f32 -> bf16x2 dword (RNE), x low, y high
__device__ inline unsigned pk2(float x, float y) {
    unsigned ux = __float_as_uint(x), uy = __float_as_uint(y);
    ux = (ux + 0x7fffu + ((ux >> 16) & 1u)) >> 16;
    uy = (uy + 0x7fffu + ((uy >> 16) & 1u)) & 0xffff0000u;
    return (ux & 0xffffu) | uy;
}

// ---------------- multisplit: partition edges into 256-node coarse bucket slabs ----
// Appends packed (src<<8 | dst&255) ints into slab b*SLAB_CAP, coalesced runs.
__global__ __launch_bounds__(256) void multisplit(const int* __restrict__ src,
                                                  const int* __restrict__ dst,
                                                  int* __restrict__ gcur,
                                                  int* __restrict__ part, int E) {
    __shared__ int cnt[512];
    __shared__ int off[512];
    __shared__ int gbase[512];
    __shared__ int img[MS_TILE];
    __shared__ int tgt[MS_TILE];
    int tid = threadIdx.x;
    for (int tbase = blockIdx.x * MS_TILE; tbase < E; tbase += gridDim.x * MS_TILE) {
        int m = min(MS_TILE, E - tbase);
        for (int i = tid; i < 512; i += 256) cnt[i] = 0;
        __syncthreads();
        int pk[8], bk[8], rk[8];
        int nloc = 0;
        int j0 = tid * 8;
        if (j0 + 8 <= m) {
            int4 s0 = *(const int4*)(src + tbase + j0);
            int4 s1 = *(const int4*)(src + tbase + j0 + 4);
            int4 d0 = *(const int4*)(dst + tbase + j0);
            int4 d1 = *(const int4*)(dst + tbase + j0 + 4);
            int ss[8] = {s0.x, s0.y, s0.z, s0.w, s1.x, s1.y, s1.z, s1.w};
            int dd[8] = {d0.x, d0.y, d0.z, d0.w, d1.x, d1.y, d1.z, d1.w};
#pragma unroll
            for (int k = 0; k < 8; k++) {
                int b = dd[k] >> 8;
                pk[k] = (ss[k] << 8) | (dd[k] & 255);
                bk[k] = b;
                rk[k] = atomicAdd(&cnt[b], 1);
            }
            nloc = 8;
        } else {
            for (int j = j0; j < m; j++) {
                int s = src[tbase + j], d = dst[tbase + j];
                int b = d >> 8;
                pk[nloc] = (s << 8) | (d & 255);
                bk[nloc] = b;
                rk[nloc] = atomicAdd(&cnt[b], 1);
                nloc++;
            }
        }
        __syncthreads();
        // exclusive scan of cnt[0..512) by wave 0 (64 lanes x 8 serial)
        if (tid < 64) {
            int base = tid * 8;
            int vals[8];
            int s0 = 0;
#pragma unroll
            for (int j = 0; j < 8; j++) { vals[j] = cnt[base + j]; s0 += vals[j]; }
            int sc = s0;
#pragma unroll
            for (int o = 1; o < 64; o <<= 1) {
                int u = __shfl_up(sc, o);
                if (tid >= o) sc += u;
            }
            int ex = sc - s0;
#pragma unroll
            for (int j = 0; j < 8; j++) { off[base + j] = ex; ex += vals[j]; }
        }
        __syncthreads();
        // reserve slab space per bucket (one atomic per WG per nonempty bucket)
        for (int b = tid; b < 512; b += 256) {
            int c = cnt[b];
            if (c) {
                int st = atomicAdd(&gcur[b], c);
                if (st > SLAB_CAP - c) st = SLAB_CAP - c;   // defensive; never in practice
                gbase[b] = b * SLAB_CAP + st;
            }
        }
        __syncthreads();
        // scatter into LDS, grouped by bucket
        for (int i = 0; i < nloc; i++) {
            int p = off[bk[i]] + rk[i];
            img[p] = pk[i];
            tgt[p] = gbase[bk[i]] + rk[i];
        }
        __syncthreads();
        // coalesced write-out (consecutive slots -> consecutive targets per bucket run)
        for (int j = tid; j < m; j += 256) part[tgt[j]] = img[j];
        __syncthreads();
    }
}

// ------- bucket_place: padded per-node CSR + rinfo + dinv from the bucket's slab -----
// Each node's list padded to a multiple of 8 with sentinel (zero-row) entries.
// csr entries are pre-shifted dword row offsets (s*32).
__global__ __launch_bounds__(256) void bucket_place(const int* __restrict__ gcur,
                                                    const int* __restrict__ part,
                                                    int2* __restrict__ rinfo,
                                                    int* __restrict__ csr,
                                                    float* __restrict__ dinv, int n) {
    __shared__ int cnt[256];
    __shared__ int cur[256];
    __shared__ int lds[256];
    __shared__ int img[CSR_CAP];
    int b = blockIdx.x;
    int tid = threadIdx.x;
    int node0 = b << 8;
    int m = min(gcur[b], SLAB_CAP);
    const int* slab = part + b * SLAB_CAP;
    cnt[tid] = 0;
    __syncthreads();
    for (int j = tid; j < m; j += 256) atomicAdd(&cnt[slab[j] & 255], 1);
    __syncthreads();
    int deg = cnt[tid];
    int pdeg = (deg + 7) & ~7;
    lds[tid] = pdeg;
    __syncthreads();
    for (int off = 1; off < 256; off <<= 1) {
        int x = (tid >= off) ? lds[tid - off] : 0;
        __syncthreads();
        lds[tid] += x;
        __syncthreads();
    }
    int ex = lds[tid] - pdeg;   // exclusive padded offset within bucket
    cur[tid] = ex;
    int mpad = lds[255];
    int node = node0 + tid;
    if (node < n) {
        rinfo[node] = make_int2(b * CSR_CAP + ex, pdeg);
        dinv[node] = rsqrtf((float)(deg + 1));  // +1 = self loop
    }
    __syncthreads();
    int sent = n << 5;          // zero-row dword offset
    for (int j = tid; j < mpad; j += 256) img[j] = sent;
    __syncthreads();
    for (int j = tid; j < m; j += 256) {
        int pkv = slab[j];
        int p = atomicAdd(&cur[pkv & 255], 1);
        img[p] = (pkv >> 8) << 5;   // dword offset of src row in t
    }
    __syncthreads();
    int* dp = csr + b * CSR_CAP;
    for (int j = tid; j < mpad; j += 256) dp[j] = img[j];   // coalesced
}

// ---- GEMM + dinv prescale: out[r] = bf16(dinv[r] * (A[r] @ W)), MFMA 16x16x32 ----
// Also writes a zero row at index nrows (sentinel target for padded edges).
template <bool AF32>
__global__ __launch_bounds__(256) void gemm64(const void* __restrict__ A_,
                                              const float* __restrict__ W,
                                              const float* __restrict__ dinv,
                                              bf16s* __restrict__ out, int nrows) {
    int lane = threadIdx.x & 63;
    int wid = (blockIdx.x * blockDim.x + threadIdx.x) >> 6;
    int nwaves = (gridDim.x * blockDim.x) >> 6;
    int r = lane & 15;       // col-in-tile
    int q = lane >> 4;       // quad
    int kb = q * 8;

    if (wid == 0) out[(size_t)nrows * 64 + lane] = __float2bfloat16(0.f);  // zero row

    // B fragments: 4 n-tiles x 2 k-halves. B[k][n]: n=lane&15, k=quad*8+j
    bf16x8 bfrag[4][2];
#pragma unroll
    for (int t = 0; t < 4; t++) {
#pragma unroll
        for (int h = 0; h < 2; h++) {
            bf16x8 bb;
            int ncol = t * 16 + r;
            int k0 = h * 32 + kb;
#pragma unroll
            for (int j = 0; j < 8; j++) bb[j] = (__bf16)W[(k0 + j) * 64 + ncol];
            bfrag[t][h] = bb;
        }
    }

    int ntiles = nrows >> 4;
    for (int tile = wid; tile < ntiles; tile += nwaves) {
        bf16x8 a0, a1;
        if (AF32) {
            const float* ap = (const float*)A_ + (size_t)(tile * 16 + r) * 64 + kb;
            f32x4 v0 = *reinterpret_cast<const f32x4*>(ap);
            f32x4 v1 = *reinterpret_cast<const f32x4*>(ap + 4);
            f32x4 v2 = *reinterpret_cast<const f32x4*>(ap + 32);
            f32x4 v3 = *reinterpret_cast<const f32x4*>(ap + 36);
#pragma unroll
            for (int j = 0; j < 4; j++) {
                a0[j] = (__bf16)v0[j]; a0[4 + j] = (__bf16)v1[j];
                a1[j] = (__bf16)v2[j]; a1[4 + j] = (__bf16)v3[j];
            }
        } else {
            const __bf16* ap = (const __bf16*)A_ + (size_t)(tile * 16 + r) * 64 + kb;
            a0 = *reinterpret_cast<const bf16x8*>(ap);
            a1 = *reinterpret_cast<const bf16x8*>(ap + 32);
        }
        f32x4 c[4];
#pragma unroll
        for (int t = 0; t < 4; t++) {
            f32x4 acc = {0.f, 0.f, 0.f, 0.f};
            acc = __builtin_amdgcn_mfma_f32_16x16x32_bf16(a0, bfrag[t][0], acc, 0, 0, 0);
            acc = __builtin_amdgcn_mfma_f32_16x16x32_bf16(a1, bfrag[t][1], acc, 0, 0, 0);
            c[t] = acc;
        }
        // C/D layout: col = lane&15, row = quad*4 + reg
        float dr[4];
#pragma unroll
        for (int g = 0; g < 4; g++) dr[g] = dinv[tile * 16 + q * 4 + g];
#pragma unroll
        for (int t = 0; t < 4; t++) {
#pragma unroll
            for (int g = 0; g < 4; g++) {
                int row = tile * 16 + q * 4 + g;
                out[(size_t)row * 64 + t * 16 + r] = __float2bfloat16(c[t][g] * dr[g]);
            }
        }
    }
}

// ---------------- aggregate (pull): half-wave (32 lanes) per node ----------------
// lane covers feats (2c, 2c+1) via dword gathers; padded lists -> no masking.
// t pre-scaled by dinv[src]: out = relu(dinv[v] * (sum_e t[s] + t[v]) + bias)
template <bool OUTF32>
__global__ __launch_bounds__(256) void aggregate(const unsigned* __restrict__ t32,
                                                 const float* __restrict__ dinv,
                                                 const int2* __restrict__ rinfo,
                                                 const int* __restrict__ csr,
                                                 const float* __restrict__ bias,
                                                 void* __restrict__ out_, int n) {
    int gid = blockIdx.x * blockDim.x + threadIdx.x;
    int v = gid >> 5;
    if (v >= n) return;
    int c = gid & 31;
    int2 ri = rinfo[v];                          // uniform across the half-wave
    unsigned sw = t32[(size_t)v * 32 + c];       // self-loop term (pre-scaled)
    float ax = uasf(sw << 16);
    float ay = uasf(sw & 0xffff0000u);
    const int* cp = csr + ri.x;                  // 32B-aligned (pdeg multiples of 8)
    for (int j = 0; j < ri.y; j += 8) {
        int4 e0 = *(const int4*)(cp + j);
        int4 e1 = *(const int4*)(cp + j + 4);
        int idx[8] = {e0.x, e0.y, e0.z, e0.w, e1.x, e1.y, e1.z, e1.w};
        unsigned g[8];
#pragma unroll
        for (int k = 0; k < 8; k++) g[k] = t32[(size_t)idx[k] + c];  // pre-shifted rows
#pragma unroll
        for (int k = 0; k < 8; k++) {
            ax += uasf(g[k] << 16);
            ay += uasf(g[k] & 0xffff0000u);
        }
    }
    float dv = dinv[v];
    float2 bb = ((const float2*)bias)[c];
    float ox = fmaxf(fmaf(dv, ax, bb.x), 0.f);
    float oy = fmaxf(fmaf(dv, ay, bb.y), 0.f);
    if (OUTF32) {
        float2 o2; o2.x = ox; o2.y = oy;
        ((float2*)out_)[(size_t)v * 32 + c] = o2;
    } else {
        ((unsigned*)out_)[(size_t)v * 32 + c] = pk2(ox, oy);
    }
}

extern "C" void kernel_launch(void* const* d_in, const int* in_sizes, int n_in,
                              void* d_out, int out_size, void* d_ws, size_t ws_size,
                              hipStream_t stream) {
    const float* x  = (const float*)d_in[0];
    const int*   ei = (const int*)d_in[1];
    const float* W1 = (const float*)d_in[2];
    const float* b1 = (const float*)d_in[3];
    const float* W2 = (const float*)d_in[4];
    const float* b2 = (const float*)d_in[5];
    float* out = (float*)d_out;

    int n = in_sizes[0] / 64;   // 100000
    int E = in_sizes[1] / 2;    // 1600000
    const int* src = ei;
    const int* dst = ei + E;
    int nbuck = (n + 255) >> 8; // 391

    // workspace carve
    char* w = (char*)d_ws;
    auto alloc = [&](size_t bytes) -> void* {
        void* p = (void*)w;
        w += (bytes + 255) & ~(size_t)255;
        return p;
    };
    int*   gcur   = (int*)alloc(2048);
    int2*  rinfo  = (int2*)alloc((size_t)n * 8);
    int*   csr    = (int*)alloc((size_t)nbuck * CSR_CAP * 4);   // ~11.2 MB
    float* dinv   = (float*)alloc((size_t)n * 4);
    // overlay: slab part shares space with tbuf — part dead after bucket_place.
    size_t slab_bytes = (size_t)nbuck * SLAB_CAP * 4;           // 8 MB
    size_t tbuf_bytes = (size_t)(n + 16) * 64 * 2;              // 12.8 MB (+zero row)
    char*  ovl    = (char*)alloc(slab_bytes > tbuf_bytes ? slab_bytes : tbuf_bytes);
    int*   part   = (int*)ovl;
    bf16s* tbuf   = (bf16s*)ovl;
    bf16s* h1     = (bf16s*)alloc((size_t)(n + 16) * 64 * 2);

    hipMemsetAsync(gcur, 0, 2048, stream);

    int ntiles = (E + MS_TILE - 1) / MS_TILE;   // 782
    multisplit<<<ntiles, 256, 0, stream>>>(src, dst, gcur, part, E);
    bucket_place<<<nbuck, 256, 0, stream>>>(gcur, part, rinfo, csr, dinv, n);

    int agrid = (n * 32 + 255) / 256;   // 12500
    // layer 1: t = bf16(dinv .* (x @ W1)); h1 = relu(aggregate) in bf16
    gemm64<true><<<256, 256, 0, stream>>>(x, W1, dinv, tbuf, n);
    aggregate<false><<<agrid, 256, 0, stream>>>((const unsigned*)tbuf, dinv, rinfo, csr, b1, h1, n);
    // layer 2: t = bf16(dinv .* (h1 @ W2)); out = relu(aggregate) in fp32
    gemm64<false><<<256, 256, 0, stream>>>(h1, W2, dinv, tbuf, n);
    aggregate<true><<<agrid, 256, 0, stream>>>((const unsigned*)tbuf, dinv, rinfo, csr, b2, out, n);
}